// Round 4
// baseline (125.855 us; speedup 1.0000x reference)
//
#include <hip/hip_runtime.h>
#include <hip/hip_fp16.h>
#include <math.h>

// RipsH1: deaths[i] = ||points[verts0[i,0]] - points[verts0[i,1]]||  (E0 rows)
//         dgm1[i,:] = ||points[verts1[i,{0,2}]] - points[verts1[i,{1,3}]]||  (E1)
// Output flat: deaths (E0 floats) then dgm1 row-major (2*E1 floats).
//
// R2 finding: time invariant in scattered-request count (8M vs 16M lane reqs,
// same 8M distinct lines, same ~45 us) -> cost is per distinct line filled.
// Theory: verts1 (32MB) + out (16MB) streaming thrashes the fp16 points table
// (1MB) out of the 4MiB/XCD L2 -> gathers served from L3. Fix: nontemporal
// (evict-first) streaming loads/stores; gathers stay cacheable. 2 rows/thread.
//
// NOTE: __builtin_nontemporal_load/store requires native clang vector types,
// not HIP_vector_type classes -> use ext_vector_type typedefs.

typedef float vfloat4 __attribute__((ext_vector_type(4)));
typedef int   vint4   __attribute__((ext_vector_type(4)));
typedef int   vint2   __attribute__((ext_vector_type(2)));
typedef unsigned int vuint4 __attribute__((ext_vector_type(4)));

__global__ __launch_bounds__(256) void cvt_kernel(
    const float* __restrict__ pts, __half* __restrict__ out, int n4) {
    int i = blockIdx.x * blockDim.x + threadIdx.x;
    if (i < n4) {
        vfloat4 f = __builtin_nontemporal_load((const vfloat4*)pts + i);
        __half2 h0 = __floats2half2_rn(f.x, f.y);
        __half2 h1 = __floats2half2_rn(f.z, f.w);
        // Regular (cacheable) stores: we WANT the table resident in L2.
        ((__half2*)out)[2 * i]     = h0;
        ((__half2*)out)[2 * i + 1] = h1;
    }
}

__device__ __forceinline__ float2 u2f2(unsigned u) {
    __half2 h = *reinterpret_cast<__half2*>(&u);
    return __half22float2(h);
}

__device__ __forceinline__ float dist8h(const vuint4* __restrict__ p, int ia, int ib) {
    vuint4 a = p[ia];   // cacheable gather: one 16B load = whole fp16 point
    vuint4 b = p[ib];
    float2 ax = u2f2(a.x), ay = u2f2(a.y), az = u2f2(a.z), aw = u2f2(a.w);
    float2 bx = u2f2(b.x), by = u2f2(b.y), bz = u2f2(b.z), bw = u2f2(b.w);
    float d0 = ax.x - bx.x, d1 = ax.y - bx.y;
    float d2 = ay.x - by.x, d3 = ay.y - by.y;
    float d4 = az.x - bz.x, d5 = az.y - bz.y;
    float d6 = aw.x - bw.x, d7 = aw.y - bw.y;
    float s = d0 * d0 + d1 * d1 + d2 * d2 + d3 * d3
            + d4 * d4 + d5 * d5 + d6 * d6 + d7 * d7;
    return sqrtf(s);
}

__global__ __launch_bounds__(256) void rips_kernel_h2(
    const __half* __restrict__ points16,
    const int* __restrict__ verts0,
    const int* __restrict__ verts1,
    float* __restrict__ out,
    int e0, int e1, int e1half) {
    int tid = blockIdx.x * blockDim.x + threadIdx.x;
    const vuint4* p = (const vuint4*)points16;
    if (tid < e1half) {
        // Two H1 rows per thread: 8 independent gathers in flight.
        const vint4* v1 = (const vint4*)verts1;
        int i0 = 2 * tid, i1 = 2 * tid + 1;
        vint4 a = __builtin_nontemporal_load(v1 + i0);
        float r0 = dist8h(p, a.x, a.y);
        float r1 = dist8h(p, a.z, a.w);
        float* o = out + e0 + 2 * i0;
        __builtin_nontemporal_store(r0, o);
        __builtin_nontemporal_store(r1, o + 1);
        if (i1 < e1) {
            vint4 b = __builtin_nontemporal_load(v1 + i1);
            float r2 = dist8h(p, b.x, b.y);
            float r3 = dist8h(p, b.z, b.w);
            __builtin_nontemporal_store(r2, o + 2);
            __builtin_nontemporal_store(r3, o + 3);
        }
    } else {
        int j = tid - e1half;
        if (j < e0) {
            vint2 v = __builtin_nontemporal_load((const vint2*)verts0 + j);
            float r = dist8h(p, v.x, v.y);
            __builtin_nontemporal_store(r, out + j);
        }
    }
}

// Fallback (f32 gathers) if ws can't hold the fp16 table.
__device__ __forceinline__ float dist8f(const float4* __restrict__ p, int ia, int ib) {
    float4 a0 = p[2 * ia], a1 = p[2 * ia + 1];
    float4 b0 = p[2 * ib], b1 = p[2 * ib + 1];
    float d0 = a0.x - b0.x, d1 = a0.y - b0.y, d2 = a0.z - b0.z, d3 = a0.w - b0.w;
    float d4 = a1.x - b1.x, d5 = a1.y - b1.y, d6 = a1.z - b1.z, d7 = a1.w - b1.w;
    return sqrtf(d0*d0 + d1*d1 + d2*d2 + d3*d3 + d4*d4 + d5*d5 + d6*d6 + d7*d7);
}

__global__ __launch_bounds__(256) void rips_kernel_f(
    const float* __restrict__ points,
    const int* __restrict__ verts0,
    const int* __restrict__ verts1,
    float* __restrict__ out,
    int e0, int e1) {
    int tid = blockIdx.x * blockDim.x + threadIdx.x;
    const float4* p = (const float4*)points;
    if (tid < e1) {
        int4 v = ((const int4*)verts1)[tid];
        out[e0 + 2 * tid]     = dist8f(p, v.x, v.y);
        out[e0 + 2 * tid + 1] = dist8f(p, v.z, v.w);
    } else {
        int j = tid - e1;
        if (j < e0) {
            int2 v = ((const int2*)verts0)[j];
            out[j] = dist8f(p, v.x, v.y);
        }
    }
}

extern "C" void kernel_launch(void* const* d_in, const int* in_sizes, int n_in,
                              void* d_out, int out_size, void* d_ws, size_t ws_size,
                              hipStream_t stream) {
    const float* points = (const float*)d_in[0];
    const int* verts0   = (const int*)d_in[1];
    const int* verts1   = (const int*)d_in[2];
    float* out = (float*)d_out;

    int npts_flat = in_sizes[0];       // 65536*8 floats
    int e0 = in_sizes[1] / 2;          // 65535
    int e1 = in_sizes[2] / 4;          // 2000000

    size_t fp16_bytes = (size_t)npts_flat * sizeof(__half);
    if (ws_size >= fp16_bytes) {
        __half* p16 = (__half*)d_ws;
        int n4 = npts_flat / 4;
        cvt_kernel<<<(n4 + 255) / 256, 256, 0, stream>>>(points, p16, n4);
        int e1half = (e1 + 1) / 2;
        int total = e1half + e0;
        int block = 256;
        int grid = (total + block - 1) / block;
        rips_kernel_h2<<<grid, block, 0, stream>>>(p16, verts0, verts1, out,
                                                   e0, e1, e1half);
    } else {
        int total = e1 + e0;
        int block = 256;
        int grid = (total + block - 1) / block;
        rips_kernel_f<<<grid, block, 0, stream>>>(points, verts0, verts1, out, e0, e1);
    }
}

// Round 5
// 116.669 us; speedup vs baseline: 1.0787x; 1.0787x over previous
//
#include <hip/hip_runtime.h>
#include <hip/hip_fp16.h>
#include <math.h>

// RipsH1: deaths[i] = ||points[verts0[i,0]] - points[verts0[i,1]]||  (E0 rows)
//         dgm1[i,:] = ||points[verts1[i,{0,2}]] - points[verts1[i,{1,3}]]||  (E1)
// Output flat: deaths (E0 floats) then dgm1 row-major (2*E1 floats).
//
// R1/R2/R4 all ~45-48us regardless of lane-request count or nt hints ->
// invariant cost is per distinct gathered line (8M fills). Two candidate
// walls at that magnitude: (a) per-CU L1 miss-fill path (~3.5cyc/fill),
// (b) L2 random-request service (~9.3 req/cyc/XCD). Distinguish by
// bypassing L1 on gathers: sc0 (agent-scope) loads skip L1 allocation,
// still hit L2. Inline asm (no HIP-level knob). nt reverted everywhere
// (R4: nt scalar stores broke write-combining, WRITE_SIZE 16.4->27.5MB).

typedef float vfloat4 __attribute__((ext_vector_type(4)));
typedef unsigned int vuint4 __attribute__((ext_vector_type(4)));

__global__ __launch_bounds__(256) void cvt_kernel(
    const float* __restrict__ pts, __half* __restrict__ out, int n4) {
    int i = blockIdx.x * blockDim.x + threadIdx.x;
    if (i < n4) {
        float4 f = ((const float4*)pts)[i];
        __half2 h0 = __floats2half2_rn(f.x, f.y);
        __half2 h1 = __floats2half2_rn(f.z, f.w);
        ((__half2*)out)[2 * i]     = h0;
        ((__half2*)out)[2 * i + 1] = h1;
    }
}

// 8 agent-scope (sc0) 16B gathers in one block: L1-bypass, one waitcnt.
// saddr form: uniform base in SGPR pair, per-lane 32-bit byte offset.
__device__ __forceinline__ void gather8_sc0(
    const __half* __restrict__ base,
    unsigned o0, unsigned o1, unsigned o2, unsigned o3,
    unsigned o4, unsigned o5, unsigned o6, unsigned o7,
    vuint4& r0, vuint4& r1, vuint4& r2, vuint4& r3,
    vuint4& r4, vuint4& r5, vuint4& r6, vuint4& r7) {
    asm volatile(
        "global_load_dwordx4 %0, %8, %16 sc0\n\t"
        "global_load_dwordx4 %1, %9, %16 sc0\n\t"
        "global_load_dwordx4 %2, %10, %16 sc0\n\t"
        "global_load_dwordx4 %3, %11, %16 sc0\n\t"
        "global_load_dwordx4 %4, %12, %16 sc0\n\t"
        "global_load_dwordx4 %5, %13, %16 sc0\n\t"
        "global_load_dwordx4 %6, %14, %16 sc0\n\t"
        "global_load_dwordx4 %7, %15, %16 sc0\n\t"
        "s_waitcnt vmcnt(0)"
        : "=&v"(r0), "=&v"(r1), "=&v"(r2), "=&v"(r3),
          "=&v"(r4), "=&v"(r5), "=&v"(r6), "=&v"(r7)
        : "v"(o0), "v"(o1), "v"(o2), "v"(o3),
          "v"(o4), "v"(o5), "v"(o6), "v"(o7),
          "s"(base)
        : "memory");
}

__device__ __forceinline__ float2 u2f2(unsigned u) {
    __half2 h = *reinterpret_cast<__half2*>(&u);
    return __half22float2(h);
}

__device__ __forceinline__ float dist8r(vuint4 a, vuint4 b) {
    float2 ax = u2f2(a.x), ay = u2f2(a.y), az = u2f2(a.z), aw = u2f2(a.w);
    float2 bx = u2f2(b.x), by = u2f2(b.y), bz = u2f2(b.z), bw = u2f2(b.w);
    float d0 = ax.x - bx.x, d1 = ax.y - bx.y;
    float d2 = ay.x - by.x, d3 = ay.y - by.y;
    float d4 = az.x - bz.x, d5 = az.y - bz.y;
    float d6 = aw.x - bw.x, d7 = aw.y - bw.y;
    return sqrtf(d0*d0 + d1*d1 + d2*d2 + d3*d3 + d4*d4 + d5*d5 + d6*d6 + d7*d7);
}

// Plain-path distance for the small E0 branch / fallback.
__device__ __forceinline__ float dist8h(const vuint4* __restrict__ p, int ia, int ib) {
    return dist8r(p[ia], p[ib]);
}

__global__ __launch_bounds__(256) void rips_kernel_sc0(
    const __half* __restrict__ points16,
    const int* __restrict__ verts0,
    const int* __restrict__ verts1,
    float* __restrict__ out,
    int e0, int e1, int nh1) {   // nh1 = ceil(e1/4); thread t does rows t+k*nh1
    int tid = blockIdx.x * blockDim.x + threadIdx.x;
    if (tid < nh1) {
        const int4* v1 = (const int4*)verts1;
        int r0 = tid;
        int r1 = tid + nh1;
        int r2 = tid + 2 * nh1;
        int r3 = tid + 3 * nh1;
        int4 a = v1[r0];                       // r0 < e1 guaranteed
        int4 b = (r1 < e1) ? v1[r1] : a;
        int4 c = (r2 < e1) ? v1[r2] : a;
        int4 d = (r3 < e1) ? v1[r3] : a;

        // Rows 0,1: 8 sc0 gathers in flight, then math + stores.
        vuint4 g0, g1, g2, g3, g4, g5, g6, g7;
        gather8_sc0(points16,
                    (unsigned)a.x << 4, (unsigned)a.y << 4,
                    (unsigned)a.z << 4, (unsigned)a.w << 4,
                    (unsigned)b.x << 4, (unsigned)b.y << 4,
                    (unsigned)b.z << 4, (unsigned)b.w << 4,
                    g0, g1, g2, g3, g4, g5, g6, g7);
        {
            float s0 = dist8r(g0, g1);
            float s1 = dist8r(g2, g3);
            float* o = out + e0 + 2 * r0;
            o[0] = s0; o[1] = s1;
        }
        if (r1 < e1) {
            float s0 = dist8r(g4, g5);
            float s1 = dist8r(g6, g7);
            float* o = out + e0 + 2 * r1;
            o[0] = s0; o[1] = s1;
        }

        // Rows 2,3.
        gather8_sc0(points16,
                    (unsigned)c.x << 4, (unsigned)c.y << 4,
                    (unsigned)c.z << 4, (unsigned)c.w << 4,
                    (unsigned)d.x << 4, (unsigned)d.y << 4,
                    (unsigned)d.z << 4, (unsigned)d.w << 4,
                    g0, g1, g2, g3, g4, g5, g6, g7);
        if (r2 < e1) {
            float s0 = dist8r(g0, g1);
            float s1 = dist8r(g2, g3);
            float* o = out + e0 + 2 * r2;
            o[0] = s0; o[1] = s1;
        }
        if (r3 < e1) {
            float s0 = dist8r(g4, g5);
            float s1 = dist8r(g6, g7);
            float* o = out + e0 + 2 * r3;
            o[0] = s0; o[1] = s1;
        }
    } else {
        int j = tid - nh1;
        if (j < e0) {
            const vuint4* p = (const vuint4*)points16;
            int2 v = ((const int2*)verts0)[j];
            out[j] = dist8h(p, v.x, v.y);
        }
    }
}

// Fallback (f32 gathers) if ws can't hold the fp16 table.
__device__ __forceinline__ float dist8f(const float4* __restrict__ p, int ia, int ib) {
    float4 a0 = p[2 * ia], a1 = p[2 * ia + 1];
    float4 b0 = p[2 * ib], b1 = p[2 * ib + 1];
    float d0 = a0.x - b0.x, d1 = a0.y - b0.y, d2 = a0.z - b0.z, d3 = a0.w - b0.w;
    float d4 = a1.x - b1.x, d5 = a1.y - b1.y, d6 = a1.z - b1.z, d7 = a1.w - b1.w;
    return sqrtf(d0*d0 + d1*d1 + d2*d2 + d3*d3 + d4*d4 + d5*d5 + d6*d6 + d7*d7);
}

__global__ __launch_bounds__(256) void rips_kernel_f(
    const float* __restrict__ points,
    const int* __restrict__ verts0,
    const int* __restrict__ verts1,
    float* __restrict__ out,
    int e0, int e1) {
    int tid = blockIdx.x * blockDim.x + threadIdx.x;
    const float4* p = (const float4*)points;
    if (tid < e1) {
        int4 v = ((const int4*)verts1)[tid];
        out[e0 + 2 * tid]     = dist8f(p, v.x, v.y);
        out[e0 + 2 * tid + 1] = dist8f(p, v.z, v.w);
    } else {
        int j = tid - e1;
        if (j < e0) {
            int2 v = ((const int2*)verts0)[j];
            out[j] = dist8f(p, v.x, v.y);
        }
    }
}

extern "C" void kernel_launch(void* const* d_in, const int* in_sizes, int n_in,
                              void* d_out, int out_size, void* d_ws, size_t ws_size,
                              hipStream_t stream) {
    const float* points = (const float*)d_in[0];
    const int* verts0   = (const int*)d_in[1];
    const int* verts1   = (const int*)d_in[2];
    float* out = (float*)d_out;

    int npts_flat = in_sizes[0];       // 65536*8 floats
    int e0 = in_sizes[1] / 2;          // 65535
    int e1 = in_sizes[2] / 4;          // 2000000

    size_t fp16_bytes = (size_t)npts_flat * sizeof(__half);
    if (ws_size >= fp16_bytes) {
        __half* p16 = (__half*)d_ws;
        int n4 = npts_flat / 4;
        cvt_kernel<<<(n4 + 255) / 256, 256, 0, stream>>>(points, p16, n4);
        int nh1 = (e1 + 3) / 4;
        int total = nh1 + e0;
        int block = 256;
        int grid = (total + block - 1) / block;
        rips_kernel_sc0<<<grid, block, 0, stream>>>(p16, verts0, verts1, out,
                                                    e0, e1, nh1);
    } else {
        int total = e1 + e0;
        int block = 256;
        int grid = (total + block - 1) / block;
        rips_kernel_f<<<grid, block, 0, stream>>>(points, verts0, verts1, out, e0, e1);
    }
}